// Round 2
// baseline (746.242 us; speedup 1.0000x reference)
//
#include <hip/hip_runtime.h>

#define HSZ 32
#define TT  1024

__device__ __forceinline__ float frcp(float x) { return __builtin_amdgcn_rcpf(x); }
// sigmoid = rcp(1 + exp(-z)); exp is v_mul+v_exp
__device__ __forceinline__ float sigm(float z) { return frcp(1.0f + __expf(-z)); }
// tanh(z) = 2*rcp(1+exp(-2z)) - 1 ; saturates to +/-1 cleanly (exp->0 or inf), no clamp
__device__ __forceinline__ float tanh_(float z) {
  return fmaf(2.0f, frcp(1.0f + __expf(-2.0f * z)), -1.0f);
}

// MLP head 32->16->8->1, h sourced from an LDS row (wave-uniform broadcast reads)
__device__ __forceinline__ float mlp_tail(const float* hrow,
                                          const float* __restrict__ W1, const float* __restrict__ b1,
                                          const float* __restrict__ W2, const float* __restrict__ b2,
                                          const float* __restrict__ W3, const float* __restrict__ b3)
{
  float a1v[16];
#pragma unroll
  for (int r = 0; r < 16; ++r) {
    float acc = b1[r];
#pragma unroll
    for (int k = 0; k < 32; ++k) acc = fmaf(W1[r * 32 + k], hrow[k], acc);
    a1v[r] = fmaxf(acc, 0.0f);
  }
  float a2v[8];
#pragma unroll
  for (int r = 0; r < 8; ++r) {
    float acc = b2[r];
#pragma unroll
    for (int k = 0; k < 16; ++k) acc = fmaf(W2[r * 16 + k], a1v[k], acc);
    a2v[r] = fmaxf(acc, 0.0f);
  }
  float o = b3[0];
#pragma unroll
  for (int k = 0; k < 8; ++k) o = fmaf(W3[k], a2v[k], o);
  return o;
}

// 256 threads = 4 waves; each wave owns FOUR batch elements as two lockstep
// pairs (A, B). Within a pair, 32 lanes = 1 element; lane j owns hidden unit j
// and keeps W_hh rows j, 32+j, 64+j, 96+j in registers (shared by both pairs).
// Pair A's LDS h-broadcast roundtrip + activation trans latency hides under
// pair B's 132-FMA phase, and vice versa (ILP instead of TLP: grid is 1024
// waves = 1 wave/SIMD, so VGPRs are free).
__global__ __launch_bounds__(256, 1)
void lstm_fused_kernel(const float* __restrict__ x,
                       const float* __restrict__ W_ih,
                       const float* __restrict__ W_hh,
                       const float* __restrict__ b_ih,
                       const float* __restrict__ b_hh,
                       const float* __restrict__ W1, const float* __restrict__ b1,
                       const float* __restrict__ W2, const float* __restrict__ b2,
                       const float* __restrict__ W3, const float* __restrict__ b3,
                       float* __restrict__ out)
{
  __shared__ __align__(16) float hlds[16][HSZ];

  const int tid  = threadIdx.x;
  const int wave = tid >> 6;
  const int lane = tid & 63;
  const int grp  = lane >> 5;               // element within lockstep pair
  const int j    = lane & 31;               // hidden unit owned by this lane
  const int rowA = wave * 4 + grp;          // block-local element / LDS row
  const int rowB = wave * 4 + 2 + grp;
  const int elemA = blockIdx.x * 16 + rowA;
  const int elemB = blockIdx.x * 16 + rowB;

  // ---- per-lane weight rows (gate order: i, f, g, o), shared by both pairs ----
  float w0[HSZ], w1[HSZ], w2[HSZ], w3[HSZ];
  {
    const float4* r0 = reinterpret_cast<const float4*>(W_hh + (0 * 32 + j) * HSZ);
    const float4* r1 = reinterpret_cast<const float4*>(W_hh + (1 * 32 + j) * HSZ);
    const float4* r2 = reinterpret_cast<const float4*>(W_hh + (2 * 32 + j) * HSZ);
    const float4* r3 = reinterpret_cast<const float4*>(W_hh + (3 * 32 + j) * HSZ);
#pragma unroll
    for (int k4 = 0; k4 < 8; ++k4) {
      float4 a = r0[k4]; w0[4*k4+0]=a.x; w0[4*k4+1]=a.y; w0[4*k4+2]=a.z; w0[4*k4+3]=a.w;
      float4 b = r1[k4]; w1[4*k4+0]=b.x; w1[4*k4+1]=b.y; w1[4*k4+2]=b.z; w1[4*k4+3]=b.w;
      float4 c4= r2[k4]; w2[4*k4+0]=c4.x;w2[4*k4+1]=c4.y;w2[4*k4+2]=c4.z;w2[4*k4+3]=c4.w;
      float4 d = r3[k4]; w3[4*k4+0]=d.x; w3[4*k4+1]=d.y; w3[4*k4+2]=d.z; w3[4*k4+3]=d.w;
    }
  }
  const float bi0 = b_ih[0 * 32 + j] + b_hh[0 * 32 + j];
  const float bi1 = b_ih[1 * 32 + j] + b_hh[1 * 32 + j];
  const float bi2 = b_ih[2 * 32 + j] + b_hh[2 * 32 + j];
  const float bi3 = b_ih[3 * 32 + j] + b_hh[3 * 32 + j];
  const float wx0 = W_ih[0 * 32 + j];   // I == 1
  const float wx1 = W_ih[1 * 32 + j];
  const float wx2 = W_ih[2 * 32 + j];
  const float wx3 = W_ih[3 * 32 + j];

  float hA[HSZ], hB[HSZ];
#pragma unroll
  for (int k = 0; k < HSZ; ++k) { hA[k] = 0.0f; hB[k] = 0.0f; }
  float cA = 0.0f, cB = 0.0f;

  const float* xrowA = x + (size_t)elemA * TT;
  const float* xrowB = x + (size_t)elemB * TT;

#pragma unroll 1
  for (int t0 = 0; t0 < TT; t0 += 32) {
    float xcA = xrowA[t0 + j];               // coalesced: 32 timesteps per load
    float xcB = xrowB[t0 + j];
#pragma unroll 1
    for (int s = 0; s < 32; ++s) {
      // issue both broadcasts early; latency hides under the FMA phases
      float xtA = __shfl(xcA, s, 32);
      float xtB = __shfl(xcB, s, 32);

      // ================= pair A =================
      {
        float a0 = bi0, a1 = bi1, a2 = bi2, a3 = bi3;
#pragma unroll
        for (int k = 0; k < HSZ; ++k) {
          a0 = fmaf(w0[k], hA[k], a0);
          a1 = fmaf(w1[k], hA[k], a1);
          a2 = fmaf(w2[k], hA[k], a2);
          a3 = fmaf(w3[k], hA[k], a3);
        }
        a0 = fmaf(xtA, wx0, a0);
        a1 = fmaf(xtA, wx1, a1);
        a2 = fmaf(xtA, wx2, a2);
        a3 = fmaf(xtA, wx3, a3);
        float si = sigm(a0), sf = sigm(a1), tg = tanh_(a2), so = sigm(a3);
        cA = fmaf(sf, cA, si * tg);
        float hj = so * tanh_(cA);
        hlds[rowA][j] = hj;                   // wave-synchronous DS, no barrier
#pragma unroll
        for (int k4 = 0; k4 < 8; ++k4) {      // broadcast read; latency hides under B
          float4 v = *reinterpret_cast<const float4*>(&hlds[rowA][4 * k4]);
          hA[4*k4+0] = v.x; hA[4*k4+1] = v.y; hA[4*k4+2] = v.z; hA[4*k4+3] = v.w;
        }
      }
      // ================= pair B =================
      {
        float a0 = bi0, a1 = bi1, a2 = bi2, a3 = bi3;
#pragma unroll
        for (int k = 0; k < HSZ; ++k) {
          a0 = fmaf(w0[k], hB[k], a0);
          a1 = fmaf(w1[k], hB[k], a1);
          a2 = fmaf(w2[k], hB[k], a2);
          a3 = fmaf(w3[k], hB[k], a3);
        }
        a0 = fmaf(xtB, wx0, a0);
        a1 = fmaf(xtB, wx1, a1);
        a2 = fmaf(xtB, wx2, a2);
        a3 = fmaf(xtB, wx3, a3);
        float si = sigm(a0), sf = sigm(a1), tg = tanh_(a2), so = sigm(a3);
        cB = fmaf(sf, cB, si * tg);
        float hj = so * tanh_(cB);
        hlds[rowB][j] = hj;
#pragma unroll
        for (int k4 = 0; k4 < 8; ++k4) {      // latency hides under next-step A
          float4 v = *reinterpret_cast<const float4*>(&hlds[rowB][4 * k4]);
          hB[4*k4+0] = v.x; hB[4*k4+1] = v.y; hB[4*k4+2] = v.z; hB[4*k4+3] = v.w;
        }
      }
    }
  }

  // ---- MLP head per element, h read from LDS rows (one-time cost) ----
  float oA = mlp_tail(&hlds[rowA][0], W1, b1, W2, b2, W3, b3);
  float oB = mlp_tail(&hlds[rowB][0], W1, b1, W2, b2, W3, b3);
  if (j == 0) {
    out[elemA] = oA;
    out[elemB] = oB;
  }
}

extern "C" void kernel_launch(void* const* d_in, const int* in_sizes, int n_in,
                              void* d_out, int out_size, void* d_ws, size_t ws_size,
                              hipStream_t stream) {
  const float* x    = (const float*)d_in[0];
  const float* W_ih = (const float*)d_in[1];
  const float* W_hh = (const float*)d_in[2];
  const float* b_ih = (const float*)d_in[3];
  const float* b_hh = (const float*)d_in[4];
  const float* W1   = (const float*)d_in[5];
  const float* b1   = (const float*)d_in[6];
  const float* W2   = (const float*)d_in[7];
  const float* b2   = (const float*)d_in[8];
  const float* W3   = (const float*)d_in[9];
  const float* b3   = (const float*)d_in[10];
  float* out = (float*)d_out;

  const int B = in_sizes[0] / TT;            // 4096
  dim3 grid(B / 16), block(256);             // 16 elements per block (4/wave)
  hipLaunchKernelGGL(lstm_fused_kernel, grid, block, 0, stream,
                     x, W_ih, W_hh, b_ih, b_hh, W1, b1, W2, b2, W3, b3, out);
}

// Round 3
// 491.941 us; speedup vs baseline: 1.5169x; 1.5169x over previous
//
#include <hip/hip_runtime.h>

#define HSZ 32
#define TT  1024

typedef float v2f __attribute__((ext_vector_type(2)));

__device__ __forceinline__ float frcp(float x) { return __builtin_amdgcn_rcpf(x); }
__device__ __forceinline__ float sigm(float z) { return frcp(1.0f + __expf(-z)); }
// tanh(z) = 2*rcp(1+exp(-2z)) - 1 ; saturates cleanly, no clamp needed
__device__ __forceinline__ float tanh_(float z) {
  return fmaf(2.0f, frcp(1.0f + __expf(-2.0f * z)), -1.0f);
}

// 256 threads = 4 waves; each wave owns TWO batch elements (lanes 0-31 = elem A,
// lanes 32-63 = elem B, SIMT-shared instructions). Lane j owns hidden unit j:
// W_hh rows j, 32+j, 64+j, 96+j live in VGPRs as float2 pairs (pinned via
// opaque asm so the compiler cannot sink the loads back into the loop), and the
// 32-deep gate dot products run as v_pk_fma_f32 chains (2 MACs/instr).
__global__ __launch_bounds__(256, 2)
void lstm_fused_kernel(const float* __restrict__ x,
                       const float* __restrict__ W_ih,
                       const float* __restrict__ W_hh,
                       const float* __restrict__ b_ih,
                       const float* __restrict__ b_hh,
                       const float* __restrict__ W1, const float* __restrict__ b1,
                       const float* __restrict__ W2, const float* __restrict__ b2,
                       const float* __restrict__ W3, const float* __restrict__ b3,
                       float* __restrict__ out)
{
  __shared__ __align__(16) float hlds[8][HSZ];

  const int tid  = threadIdx.x;
  const int wave = tid >> 6;
  const int lane = tid & 63;
  const int grp  = lane >> 5;               // element within wave
  const int j    = lane & 31;               // hidden unit owned by this lane
  const int we   = wave * 2 + grp;          // block-local element / LDS row
  const int elem = blockIdx.x * 8 + we;     // batch element

  // ---- per-lane weight rows (gate order: i, f, g, o) as float2 pairs ----
  v2f w0[16], w1[16], w2[16], w3[16];
  {
    const float4* r0 = reinterpret_cast<const float4*>(W_hh + (0 * 32 + j) * HSZ);
    const float4* r1 = reinterpret_cast<const float4*>(W_hh + (1 * 32 + j) * HSZ);
    const float4* r2 = reinterpret_cast<const float4*>(W_hh + (2 * 32 + j) * HSZ);
    const float4* r3 = reinterpret_cast<const float4*>(W_hh + (3 * 32 + j) * HSZ);
#pragma unroll
    for (int k4 = 0; k4 < 8; ++k4) {
      float4 a = r0[k4]; w0[2*k4] = (v2f){a.x, a.y}; w0[2*k4+1] = (v2f){a.z, a.w};
      float4 b = r1[k4]; w1[2*k4] = (v2f){b.x, b.y}; w1[2*k4+1] = (v2f){b.z, b.w};
      float4 c = r2[k4]; w2[2*k4] = (v2f){c.x, c.y}; w2[2*k4+1] = (v2f){c.z, c.w};
      float4 d = r3[k4]; w3[2*k4] = (v2f){d.x, d.y}; w3[2*k4+1] = (v2f){d.z, d.w};
    }
  }
  // pin: stop the compiler from rematerializing these loads inside the t-loop
#pragma unroll
  for (int k = 0; k < 16; ++k) {
    asm volatile("" : "+v"(w0[k]), "+v"(w1[k]), "+v"(w2[k]), "+v"(w3[k]));
  }

  const float bi0 = b_ih[0 * 32 + j] + b_hh[0 * 32 + j];
  const float bi1 = b_ih[1 * 32 + j] + b_hh[1 * 32 + j];
  const float bi2 = b_ih[2 * 32 + j] + b_hh[2 * 32 + j];
  const float bi3 = b_ih[3 * 32 + j] + b_hh[3 * 32 + j];
  const float wx0 = W_ih[0 * 32 + j];   // I == 1
  const float wx1 = W_ih[1 * 32 + j];
  const float wx2 = W_ih[2 * 32 + j];
  const float wx3 = W_ih[3 * 32 + j];

  v2f h2[16];
#pragma unroll
  for (int k = 0; k < 16; ++k) h2[k] = (v2f){0.0f, 0.0f};
  float c = 0.0f;

  const float* xrow = x + (size_t)elem * TT;

#pragma unroll 1
  for (int t0 = 0; t0 < TT; t0 += 32) {
    float xc = xrow[t0 + j];                 // coalesced: 32 timesteps per load
#pragma unroll 1
    for (int s = 0; s < 32; ++s) {
      float xt = __shfl(xc, s, 32);          // broadcast x_t within 32-lane group

      v2f acc0 = (v2f){bi0, 0.0f};
      v2f acc1 = (v2f){bi1, 0.0f};
      v2f acc2 = (v2f){bi2, 0.0f};
      v2f acc3 = (v2f){bi3, 0.0f};
#pragma unroll
      for (int k = 0; k < 16; ++k) {
        acc0 = __builtin_elementwise_fma(w0[k], h2[k], acc0);
        acc1 = __builtin_elementwise_fma(w1[k], h2[k], acc1);
        acc2 = __builtin_elementwise_fma(w2[k], h2[k], acc2);
        acc3 = __builtin_elementwise_fma(w3[k], h2[k], acc3);
      }
      // xt enters at the END so the shfl latency hides under the pk chain
      float a0 = acc0.x + fmaf(xt, wx0, acc0.y);
      float a1 = acc1.x + fmaf(xt, wx1, acc1.y);
      float a2 = acc2.x + fmaf(xt, wx2, acc2.y);
      float a3 = acc3.x + fmaf(xt, wx3, acc3.y);

      float si = sigm(a0), sf = sigm(a1), tg = tanh_(a2), so = sigm(a3);
      c = fmaf(sf, c, si * tg);
      float hj = so * tanh_(c);

      // broadcast new h across the 32-lane group via LDS (wave-synchronous
      // in-order DS pipe; each wave owns disjoint rows -> no barrier)
      hlds[we][j] = hj;
#pragma unroll
      for (int k4 = 0; k4 < 8; ++k4) {
        float4 v = *reinterpret_cast<const float4*>(&hlds[we][4 * k4]);
        h2[2*k4]   = (v2f){v.x, v.y};
        h2[2*k4+1] = (v2f){v.z, v.w};
      }
    }
  }

  // ---- MLP head 32->16->8->1 on the final h (LDS row, broadcast reads) ----
  const float* hrow = &hlds[we][0];
  float a1v[16];
#pragma unroll
  for (int r = 0; r < 16; ++r) {
    float acc = b1[r];
#pragma unroll
    for (int k = 0; k < 32; ++k) acc = fmaf(W1[r * 32 + k], hrow[k], acc);
    a1v[r] = fmaxf(acc, 0.0f);
  }
  float a2v[8];
#pragma unroll
  for (int r = 0; r < 8; ++r) {
    float acc = b2[r];
#pragma unroll
    for (int k = 0; k < 16; ++k) acc = fmaf(W2[r * 16 + k], a1v[k], acc);
    a2v[r] = fmaxf(acc, 0.0f);
  }
  float o = b3[0];
#pragma unroll
  for (int k = 0; k < 8; ++k) o = fmaf(W3[k], a2v[k], o);

  if (j == 0) out[elem] = o;
}

extern "C" void kernel_launch(void* const* d_in, const int* in_sizes, int n_in,
                              void* d_out, int out_size, void* d_ws, size_t ws_size,
                              hipStream_t stream) {
  const float* x    = (const float*)d_in[0];
  const float* W_ih = (const float*)d_in[1];
  const float* W_hh = (const float*)d_in[2];
  const float* b_ih = (const float*)d_in[3];
  const float* b_hh = (const float*)d_in[4];
  const float* W1   = (const float*)d_in[5];
  const float* b1   = (const float*)d_in[6];
  const float* W2   = (const float*)d_in[7];
  const float* b2   = (const float*)d_in[8];
  const float* W3   = (const float*)d_in[9];
  const float* b3   = (const float*)d_in[10];
  float* out = (float*)d_out;

  const int B = in_sizes[0] / TT;            // 4096
  dim3 grid(B / 8), block(256);              // 8 elements per block (2/wave)
  hipLaunchKernelGGL(lstm_fused_kernel, grid, block, 0, stream,
                     x, W_ih, W_hh, b_ih, b_hh, W1, b1, W2, b2, W3, b3, out);
}